// Round 8
// baseline (132.362 us; speedup 1.0000x reference)
//
#include <hip/hip_runtime.h>

// Attention_73375221285454: fused MHA block on MI355X (gfx950)
// B=4 N=2048 D=768 H=12 DH=64. fp32 in/out, bf16 MFMA internally.
// Round 8: T4 counted-vmcnt in k_gemm: raw s_barrier (no vmcnt(0) drain) +
// s_waitcnt vmcnt(8) waiting only for tile-t's own stage (issued one full
// iteration earlier) while tile-t+1's 8 loads stay in flight across the
// barrier. This attacks the measured ~5070 cyc/K-step (vs ~1230 cyc work):
// the __syncthreads-emitted vmcnt(0) was draining freshly-issued loads every
// step (m233's 2-phase stall). Everything else identical to round 7.

#define B_ 4
#define N_ 2048
#define D_ 768
#define H_ 12
#define DH_ 64
#define CSC_ 0.18033688011112042f  // SCALE * log2(e)

typedef __attribute__((ext_vector_type(8))) short bf8_t;   // 8 bf16 (MFMA A/B frag)
typedef __attribute__((ext_vector_type(4))) float f4_t;    // 16x16 C/D frag
typedef __attribute__((ext_vector_type(16))) float f16v;   // 32x32 C/D frag
typedef __attribute__((ext_vector_type(4))) int i4_t;

__device__ __forceinline__ short f2b(float f) {            // fp32 -> bf16 RNE
  union { float f; unsigned u; } v; v.f = f;
  unsigned r = v.u + 0x7FFFu + ((v.u >> 16) & 1u);
  return (short)(r >> 16);
}
__device__ __forceinline__ float b2f(short s) {
  union { unsigned u; float f; } v; v.u = ((unsigned)(unsigned short)s) << 16;
  return v.f;
}
__device__ __forceinline__ unsigned cvtpk(float lo, float hi) {
  unsigned r;
  asm("v_cvt_pk_bf16_f32 %0, %1, %2" : "=v"(r) : "v"(lo), "v"(hi));
  return r;
}
__device__ __forceinline__ void plswap(unsigned& a, unsigned& b) {
  asm("v_permlane32_swap_b32 %0, %1" : "+v"(a), "+v"(b));
}
__device__ __forceinline__ float max3f(float a, float b, float c) {
  float r;
  asm("v_max3_f32 %0, %1, %2, %3" : "=v"(r) : "v"(a), "v"(b), "v"(c));
  return r;
}

#define GLOAD_LDS16(gp, lp)                                                       \
  __builtin_amdgcn_global_load_lds(                                               \
      (const __attribute__((address_space(1))) void*)(gp),                        \
      (__attribute__((address_space(3))) void*)(lp), 16, 0, 0)

// ---------------- prep: x fp32 -> bf16 (BW-bound floor ~6us) ----------------
__global__ __launch_bounds__(256) void k_convx(const float* __restrict__ x,
                                               short* __restrict__ xb) {
  int i = blockIdx.x * 256 + threadIdx.x;
  int base = i * 8;
  float4 a = *(const float4*)(x + base);
  float4 b = *(const float4*)(x + base + 4);
  bf8_t v;
  v[0] = f2b(a.x); v[1] = f2b(a.y); v[2] = f2b(a.z); v[3] = f2b(a.w);
  v[4] = f2b(b.x); v[5] = f2b(b.y); v[6] = f2b(b.z); v[7] = f2b(b.w);
  *(bf8_t*)(xb + base) = v;
}

// ------- prep: transpose weights fp32->bf16 into B^T layout; Wq pre-scaled -------
__global__ __launch_bounds__(256) void k_wtrans(const float* __restrict__ Wq,
                                                const float* __restrict__ Wk,
                                                const float* __restrict__ Wv,
                                                const float* __restrict__ Wo,
                                                short* __restrict__ WqkvT,
                                                short* __restrict__ WoT) {
  int z = blockIdx.z;
  const float* W = (z == 0) ? Wq : (z == 1) ? Wk : (z == 2) ? Wv : Wo;
  short* dst = (z < 3) ? (WqkvT + (size_t)z * D_ * D_) : WoT;
  float sc = (z == 0) ? CSC_ : 1.f;
  __shared__ float T[64][65];
  int r0 = blockIdx.y * 64, c0 = blockIdx.x * 64;
  int tr = threadIdx.x >> 6, tc = threadIdx.x & 63;
#pragma unroll
  for (int i = 0; i < 16; ++i) {
    int r = tr + i * 4;
    T[r][tc] = W[(size_t)(r0 + r) * D_ + c0 + tc];
  }
  __syncthreads();
#pragma unroll
  for (int i = 0; i < 16; ++i) {
    int r = tr + i * 4;
    dst[(size_t)(c0 + r) * D_ + r0 + tc] = f2b(T[tc][r] * sc);
  }
}

// ------- GEMM (dbuf gload_lds + counted vmcnt): C = A[M x K] * BT[Ncol x K]^T -------
// 128x128 tile, BK=64, 4 waves. Per K-step: issue STAGE(t+1) [8 loads], then
// s_waitcnt vmcnt(8) (waits ONLY tile-t's loads, issued a full iter ago),
// raw s_barrier (no drain), compute, raw s_barrier. Tile-t+1 loads remain in
// flight across both barriers (T4). XOR-swizzle as round 7 (0 conflicts).
template <int MODE>
__global__ __launch_bounds__(256) void k_gemm(const short* __restrict__ A,
                                              const short* __restrict__ BT, int K,
                                              short* __restrict__ Qb, short* __restrict__ Kb,
                                              short* __restrict__ Vb,
                                              float* __restrict__ Cout, int ldc) {
  __shared__ short As[2][128 * 64];  // 2 x 16KB
  __shared__ short Bs[2][128 * 64];  // 2 x 16KB
  // T1: bijective XCD swizzle (nwg % 8 == 0 for both launches)
  int gx = gridDim.x;
  int nwg = gx * gridDim.y;
  int flat = blockIdx.y * gx + blockIdx.x;
  int cpx = nwg >> 3;
  int swzb = (flat & 7) * cpx + (flat >> 3);
  int row0 = (swzb / gx) * 128, col0 = (swzb % gx) * 128;

  int tid = threadIdx.x, lane = tid & 63, w = tid >> 6;
  int wr = w >> 1, wc = w & 1;
  int lr = lane & 15, lhi = lane >> 4;
  f4_t acc[4][4];
#pragma unroll
  for (int mi = 0; mi < 4; ++mi)
#pragma unroll
    for (int ni = 0; ni < 4; ++ni) acc[mi][ni] = (f4_t){0.f, 0.f, 0.f, 0.f};

  int sub = lane >> 3;
  int scb = ((lane & 7) * 16) ^ (sub << 4);  // pre-swizzled global byte col
  auto STAGE = [&](int k0, int buf) {
    char* ab = (char*)As[buf] + (w << 12);
    char* bb = (char*)Bs[buf] + (w << 12);
#pragma unroll
    for (int i = 0; i < 4; ++i) {
      int r = 32 * w + 8 * i + sub;
      GLOAD_LDS16((const char*)(A + (size_t)(row0 + r) * K + k0) + scb, ab + (i << 10));
      GLOAD_LDS16((const char*)(BT + (size_t)(col0 + r) * K + k0) + scb, bb + (i << 10));
    }
  };

  STAGE(0, 0);

  int nt = K / 64;
  for (int t = 0; t < nt; ++t) {
    int cur = t & 1;
    if (t + 1 < nt) {
      STAGE((t + 1) * 64, cur ^ 1);  // 8 loads in flight across barriers (T4)
      asm volatile("s_waitcnt vmcnt(8)" ::: "memory");  // tile-t loads done
    } else {
      asm volatile("s_waitcnt vmcnt(0)" ::: "memory");
    }
    __builtin_amdgcn_sched_barrier(0);
    __builtin_amdgcn_s_barrier();   // buf[cur] published to all waves

    const char* Ac = (const char*)As[cur];
    const char* Bc = (const char*)Bs[cur];
    int rsw = (lr & 7) << 4;  // read-side XOR (row & 7 == lr & 7)
#pragma unroll
    for (int kc = 0; kc < 2; ++kc) {
      bf8_t av[4], bv[4];
#pragma unroll
      for (int mi = 0; mi < 4; ++mi) {
        int row = 64 * wr + 16 * mi + lr;
        av[mi] = *(const bf8_t*)(Ac + row * 128 + ((64 * kc + 16 * lhi) ^ rsw));
      }
#pragma unroll
      for (int ni = 0; ni < 4; ++ni) {
        int row = 64 * wc + 16 * ni + lr;
        bv[ni] = *(const bf8_t*)(Bc + row * 128 + ((64 * kc + 16 * lhi) ^ rsw));
      }
#pragma unroll
      for (int mi = 0; mi < 4; ++mi)
#pragma unroll
        for (int ni = 0; ni < 4; ++ni)
          acc[mi][ni] = __builtin_amdgcn_mfma_f32_16x16x32_bf16(av[mi], bv[ni], acc[mi][ni], 0, 0, 0);
    }
    __builtin_amdgcn_sched_barrier(0);
    __builtin_amdgcn_s_barrier();   // all waves done reading buf[cur] before
                                    // next iter's STAGE overwrites it
  }

#pragma unroll
  for (int mi = 0; mi < 4; ++mi)
#pragma unroll
    for (int ni = 0; ni < 4; ++ni)
#pragma unroll
      for (int r = 0; r < 4; ++r) {
        int row = row0 + 64 * wr + 16 * mi + 4 * lhi + r;
        int col = col0 + 64 * wc + 16 * ni + lr;
        float v = acc[mi][ni][r];
        if (MODE == 0) {
          int which = col / 768;
          int cc2 = col - which * 768;
          int h = cc2 >> 6, dh = cc2 & 63;
          int b = row >> 11, n = row & 2047;
          size_t dst = (((size_t)(b * H_ + h)) * N_ + n) * DH_ + dh;
          short bv2 = f2b(v);
          if (which == 0) Qb[dst] = bv2;
          else if (which == 1) Kb[dst] = bv2;
          else Vb[dst] = bv2;
        } else {
          Cout[(size_t)row * ldc + col] = v;
        }
      }
}

// ---------------- per-batch valid-index list (order-preserving scan) ----------------
__global__ __launch_bounds__(256) void k_maskidx(const int* __restrict__ xmask,
                                                 int* __restrict__ idx,
                                                 int* __restrict__ cnt) {
  int b = blockIdx.x, t = threadIdx.x;
  const int* mp = xmask + b * N_;
  int loc[8], c = 0;
#pragma unroll
  for (int j = 0; j < 8; ++j) {
    int n = t * 8 + j;
    if (mp[n]) loc[c++] = n;
  }
  __shared__ int sc[256];
  sc[t] = c;
  __syncthreads();
  for (int off = 1; off < 256; off <<= 1) {
    int v = (t >= off) ? sc[t - off] : 0;
    __syncthreads();
    sc[t] += v;
    __syncthreads();
  }
  int base = sc[t] - c;
  int* op = idx + b * N_;
  for (int j = 0; j < c; ++j) op[base + j] = loc[j];
  if (t == 255) cnt[b] = sc[255];
}

// ---------------- Vmean stage A: per-(bh,chunk) partial sums (deterministic) ----------------
__global__ __launch_bounds__(256) void k_vmeanA(const short* __restrict__ Vb,
                                                float* __restrict__ part) {
  int bh = blockIdx.y, ch = blockIdx.x, t = threadIdx.x;
  int rg = t >> 3, cg = t & 7;
  const short* vp = Vb + ((size_t)bh * N_ + ch * 256 + rg) * DH_ + cg * 8;
  float a[8] = {0, 0, 0, 0, 0, 0, 0, 0};
#pragma unroll
  for (int k = 0; k < 8; ++k) {
    bf8_t v = *(const bf8_t*)(vp + (size_t)32 * k * DH_);
#pragma unroll
    for (int e = 0; e < 8; ++e) a[e] += b2f(v[e]);
  }
  __shared__ float red[8][32][8];
#pragma unroll
  for (int e = 0; e < 8; ++e) red[cg][rg][e] = a[e];
  __syncthreads();
  if (t < 64) {
    int g = t >> 3, j = t & 7;
    float s = 0;
#pragma unroll
    for (int i = 0; i < 32; ++i) s += red[g][i][j];
    part[((size_t)bh * 8 + ch) * 64 + g * 8 + j] = s;
  }
}

// ---------------- Vmean stage B: reduce 8 partials ----------------
__global__ __launch_bounds__(256) void k_vmeanB(const float* __restrict__ part,
                                                float* __restrict__ Vmean) {
  int i = blockIdx.x * 256 + threadIdx.x;
  if (i >= 48 * 64) return;
  int bh = i >> 6, dh = i & 63;
  float s = 0;
#pragma unroll
  for (int c = 0; c < 8; ++c) s += part[((size_t)bh * 8 + c) * 64 + dh];
  Vmean[i] = s * (1.f / 2048.f);
}

// -------- gather K,V by idx into compacted Kc[bh][j][dh], Vtc[bh][dh][j] --------
__global__ __launch_bounds__(256) void k_gather(const short* __restrict__ Kb,
                                                const short* __restrict__ Vb,
                                                const int* __restrict__ idx,
                                                const int* __restrict__ cnt,
                                                short* __restrict__ Kc,
                                                short* __restrict__ Vtc) {
  int bh = blockIdx.y, b = bh / H_;
  int j0 = blockIdx.x * 64;
  int cn = cnt[b];
  int cp = (cn + 63) & ~63;
  if (j0 >= cp) return;
  int t = threadIdx.x;
  __shared__ int sidx[64];
  __shared__ short vt[64][72];
  if (t < 64) sidx[t] = (j0 + t < cn) ? idx[b * N_ + j0 + t] : -1;
  __syncthreads();
  int r = t >> 2, c16 = (t & 3) * 16;
  int src = sidx[r];
  const bf8_t zz = {0, 0, 0, 0, 0, 0, 0, 0};
#pragma unroll
  for (int u = 0; u < 2; ++u) {
    bf8_t kv = (src >= 0) ? *(const bf8_t*)(Kb + ((size_t)bh * N_ + src) * DH_ + c16 + u * 8) : zz;
    bf8_t vv = (src >= 0) ? *(const bf8_t*)(Vb + ((size_t)bh * N_ + src) * DH_ + c16 + u * 8) : zz;
    *(bf8_t*)(Kc + ((size_t)bh * N_ + j0 + r) * DH_ + c16 + u * 8) = kv;
    *(bf8_t*)(&vt[r][c16 + u * 8]) = vv;
  }
  __syncthreads();
  int dh = t >> 2;
#pragma unroll
  for (int u = 0; u < 2; ++u) {
    bf8_t ov;
#pragma unroll
    for (int e = 0; e < 8; ++e) ov[e] = vt[c16 + u * 8 + e][dh];
    *(bf8_t*)(Vtc + ((size_t)bh * DH_ + dh) * N_ + j0 + c16 + u * 8) = ov;
  }
}

// -------- fill masked-q rows of Ao with Vmean (uniform-softmax result) --------
__global__ __launch_bounds__(256) void k_fill(const int* __restrict__ xmask,
                                              const float* __restrict__ Vmean,
                                              short* __restrict__ Ao) {
  int b = blockIdx.y;
  int n = blockIdx.x * 32 + (threadIdx.x >> 3);
  int cg = threadIdx.x & 7;
  if (xmask[b * N_ + n]) return;
#pragma unroll
  for (int k = 0; k < 12; ++k) {
    int col = cg * 8 + k * 64;
    int h = col >> 6, dh = col & 63;
    const float* vp = Vmean + ((size_t)b * H_ + h) * 64 + dh;
    bf8_t ov;
#pragma unroll
    for (int e = 0; e < 8; ++e) ov[e] = f2b(vp[e]);
    *(bf8_t*)(Ao + ((size_t)b * N_ + n) * D_ + col) = ov;
  }
}

// -------- flash attention on COMPACTED q/k (swapped-QK^T 32x32) --------
__global__ __launch_bounds__(256, 3) void k_attn(const short* __restrict__ Q,
                                                 const short* __restrict__ Kcg,
                                                 const short* __restrict__ Vtcg,
                                                 const int* __restrict__ idx,
                                                 const int* __restrict__ cnt,
                                                 short* __restrict__ Aout) {
  int bh = blockIdx.y;
  int b = bh / H_, h = bh - b * H_;
  int cn = cnt[b];
  int nqt = (cn + 127) >> 7;
  if ((int)blockIdx.x >= nqt) return;  // block-uniform exit
  int nkt = (cn + 63) >> 6;
  const short* Qp = Q + (size_t)bh * N_ * DH_;
  const short* Kp = Kcg + (size_t)bh * N_ * DH_;
  const short* Vp = Vtcg + (size_t)bh * DH_ * N_;
  const int* ip = idx + b * N_;
  int q0 = blockIdx.x * 128;
  int tid = threadIdx.x, lane = tid & 63, w = tid >> 6;
  int lq = lane & 31, hi = lane >> 5;

  __shared__ char smem[32768];

  int qrow = q0 + 32 * w + lq;
  int qn = ip[qrow < cn ? qrow : cn - 1];  // clamp tail (stores guarded later)

  bf8_t qf[4];
#pragma unroll
  for (int kc = 0; kc < 4; ++kc)
    qf[kc] = *(const bf8_t*)(Qp + (size_t)qn * DH_ + 16 * kc + 8 * hi);

  short NEGBIG = f2b(-1e30f);
  bf8_t qbf = {hi ? (short)0 : (short)0x3F80, 0, 0, 0, 0, 0, 0, 0};  // bias B (1.0)

  f16v acco[2];
#pragma unroll
  for (int i = 0; i < 16; ++i) { acco[0][i] = 0.f; acco[1][i] = 0.f; }
  float m = -1e29f, lsum = 0.f;

  auto STAGE = [&](int key0, int buf) {
    char* kb_ = smem + buf * 16384;
    char* vb_ = kb_ + 8192;
    int row = tid >> 3;
    int cb = (tid & 7) * 16;
    char* lk = kb_ + ((tid >> 6) << 10);
    char* lv = vb_ + ((tid >> 6) << 10);
#pragma unroll
    for (int rr = 0; rr < 2; ++rr) {
      int r2 = row + rr * 32;
      int sw = cb ^ ((r2 & 7) << 4);
      GLOAD_LDS16((const char*)(Kp + (size_t)(key0 + r2) * DH_) + sw, lk + rr * 4096);
      GLOAD_LDS16((const char*)(Vp + (size_t)r2 * N_ + key0) + sw, lv + rr * 4096);
    }
  };

  STAGE(0, 0);
  __syncthreads();

  for (int kt = 0; kt < nkt; ++kt) {
    int cur = kt & 1;
    if (kt + 1 < nkt) STAGE((kt + 1) * 64, cur ^ 1);

    const char* kbase = smem + cur * 16384;
    const char* vbase = kbase + 8192;
    int key0 = kt * 64;

    f16v accs[2];
#pragma unroll
    for (int i = 0; i < 16; ++i) { accs[0][i] = 0.f; accs[1][i] = 0.f; }
    int swz = (lq & 7) << 4;
    __builtin_amdgcn_s_setprio(1);
#pragma unroll
    for (int kc = 0; kc < 4; ++kc) {
      int colb = (32 * kc + 16 * hi) ^ swz;
      bf8_t k0 = *(const bf8_t*)(kbase + lq * 128 + colb);
      bf8_t k1 = *(const bf8_t*)(kbase + (32 + lq) * 128 + colb);
      accs[0] = __builtin_amdgcn_mfma_f32_32x32x16_bf16(k0, qf[kc], accs[0], 0, 0, 0);
      accs[1] = __builtin_amdgcn_mfma_f32_32x32x16_bf16(k1, qf[kc], accs[1], 0, 0, 0);
    }
    __builtin_amdgcn_s_setprio(0);
    if (key0 + 64 > cn) {  // tail guard: keys j >= cn get -1e30 bias
      bf8_t bf0 = {(hi || key0 + lq < cn) ? (short)0 : NEGBIG, 0, 0, 0, 0, 0, 0, 0};
      bf8_t bf1 = {(hi || key0 + 32 + lq < cn) ? (short)0 : NEGBIG, 0, 0, 0, 0, 0, 0, 0};
      accs[0] = __builtin_amdgcn_mfma_f32_32x32x16_bf16(bf0, qbf, accs[0], 0, 0, 0);
      accs[1] = __builtin_amdgcn_mfma_f32_32x32x16_bf16(bf1, qbf, accs[1], 0, 0, 0);
    }

    float mx = max3f(accs[0][0], accs[0][1], accs[0][2]);
#pragma unroll
    for (int i = 3; i < 15; i += 2) mx = max3f(mx, accs[0][i], accs[0][i + 1]);
    mx = max3f(mx, accs[0][15], accs[1][0]);
#pragma unroll
    for (int i = 1; i < 15; i += 2) mx = max3f(mx, accs[1][i], accs[1][i + 1]);
    mx = fmaxf(mx, accs[1][15]);
    mx = fmaxf(mx, __shfl_xor(mx, 32));
    if (!__all(mx <= m + 8.f)) {
      float mnew = fmaxf(m, mx);
      float sc = __builtin_amdgcn_exp2f(m - mnew);
      m = mnew;
      lsum *= sc;
#pragma unroll
      for (int i = 0; i < 16; ++i) { acco[0][i] *= sc; acco[1][i] *= sc; }
    }
    float psa[4] = {0.f, 0.f, 0.f, 0.f};
#pragma unroll
    for (int kb2 = 0; kb2 < 2; ++kb2)
#pragma unroll
      for (int r = 0; r < 16; ++r) {
        float p = __builtin_amdgcn_exp2f(accs[kb2][r] - m);
        accs[kb2][r] = p;
        psa[r & 3] += p;
      }
    float ps = (psa[0] + psa[1]) + (psa[2] + psa[3]);
    ps += __shfl_xor(ps, 32);
    lsum += ps;

    __builtin_amdgcn_s_setprio(1);
#pragma unroll
    for (int kc = 0; kc < 4; ++kc) {
      int kb2 = kc >> 1, rb = (kc & 1) * 8;
      unsigned a_ = cvtpk(accs[kb2][rb + 0], accs[kb2][rb + 1]);
      unsigned b_ = cvtpk(accs[kb2][rb + 4], accs[kb2][rb + 5]);
      unsigned c_ = cvtpk(accs[kb2][rb + 2], accs[kb2][rb + 3]);
      unsigned d_ = cvtpk(accs[kb2][rb + 6], accs[kb2][rb + 7]);
      plswap(a_, b_);
      plswap(c_, d_);
      union { i4_t i; bf8_t v; } pu;
      pu.i = (i4_t){(int)a_, (int)c_, (int)b_, (int)d_};
      int colb = (32 * kc + 16 * hi) ^ swz;
      bf8_t v0 = *(const bf8_t*)(vbase + lq * 128 + colb);
      bf8_t v1 = *(const bf8_t*)(vbase + (32 + lq) * 128 + colb);
      acco[0] = __builtin_amdgcn_mfma_f32_32x32x16_bf16(v0, pu.v, acco[0], 0, 0, 0);
      acco[1] = __builtin_amdgcn_mfma_f32_32x32x16_bf16(v1, pu.v, acco[1], 0, 0, 0);
    }
    __builtin_amdgcn_s_setprio(0);

    __syncthreads();
  }
  __syncthreads();  // all waves done with K/V buffers before Os reuse

  float inv = 1.f / lsum;
  unsigned* Os = (unsigned*)smem + w * 1152;
#pragma unroll
  for (int dhb = 0; dhb < 2; ++dhb)
#pragma unroll
    for (int r = 0; r < 16; r += 2) {
      unsigned pk = cvtpk(acco[dhb][r] * inv, acco[dhb][r + 1] * inv);
      int colu = 16 * dhb + ((r & 3) >> 1) + 4 * (r >> 2) + 2 * hi;
      Os[lq * 36 + colu] = pk;
    }
#pragma unroll
  for (int it = 0; it < 4; ++it) {
    int q = (lane >> 3) + 8 * it;
    int qr2 = q0 + 32 * w + q;
    if (qr2 < cn) {
      int n = ip[qr2];
      i4_t vv = *(const i4_t*)(Os + q * 36 + 4 * (lane & 7));
      union { i4_t i; bf8_t s; } u2;
      u2.i = vv;
      size_t off = ((size_t)b * N_ + n) * D_ + h * DH_ + 8 * (lane & 7);
      *(bf8_t*)(Aout + off) = u2.s;
    }
  }
}

extern "C" void kernel_launch(void* const* d_in, const int* in_sizes, int n_in,
                              void* d_out, int out_size, void* d_ws, size_t ws_size,
                              hipStream_t stream) {
  (void)in_sizes; (void)n_in; (void)out_size; (void)ws_size;
  const float* x  = (const float*)d_in[0];
  const int*   xm = (const int*)d_in[1];
  const float* Wq = (const float*)d_in[2];
  const float* Wk = (const float*)d_in[3];
  const float* Wv = (const float*)d_in[4];
  const float* Wo = (const float*)d_in[5];
  float* out = (float*)d_out;
  char* ws = (char*)d_ws;

  short* x_bf  = (short*)(ws + 0);         // x_bf during QKV-GEMM...
  short* Ao    = (short*)(ws + 0);         // ...then reused as attn output
  short* WqkvT = (short*)(ws + 12582912);
  int*   idxb  = (int*)(ws + 12582912);    // aux overlays WqkvT after gemm<0>
  int*   cntb  = (int*)(ws + 12615680);
  float* part  = (float*)(ws + 12615744);
  float* Vmean = (float*)(ws + 12714048);
  short* WoT   = (short*)(ws + 16121856);
  short* Qb    = (short*)(ws + 17301504);
  short* Kb    = (short*)(ws + 29884416);
  short* Vb    = (short*)(ws + 42467328);
  short* Kc    = (short*)(ws + 55050240);
  short* Vtc   = (short*)(ws + 67633152);

  k_convx<<<3072, 256, 0, stream>>>(x, x_bf);
  k_wtrans<<<dim3(12, 12, 4), 256, 0, stream>>>(Wq, Wk, Wv, Wo, WqkvT, WoT);
  k_gemm<0><<<dim3(18, 64), 256, 0, stream>>>(x_bf, WqkvT, 768, Qb, Kb, Vb, nullptr, 0);
  k_maskidx<<<4, 256, 0, stream>>>(xm, idxb, cntb);
  k_vmeanA<<<dim3(8, 48), 256, 0, stream>>>(Vb, part);
  k_vmeanB<<<12, 256, 0, stream>>>(part, Vmean);
  k_gather<<<dim3(32, 48), 256, 0, stream>>>(Kb, Vb, idxb, cntb, Kc, Vtc);
  k_attn<<<dim3(16, 48), 256, 0, stream>>>(Qb, Kc, Vtc, idxb, cntb, Ao);
  k_fill<<<dim3(64, 4), 256, 0, stream>>>(xm, Vmean, Ao);
  k_gemm<1><<<dim3(6, 64), 256, 0, stream>>>(Ao, WoT, 768, nullptr, nullptr, nullptr, out, 768);
}